// Round 6
// baseline (331.060 us; speedup 1.0000x reference)
//
#include <hip/hip_runtime.h>
#include <hip/hip_bf16.h>

#define NN 100000
#define NE 1600000
#define DF 128
#define NB 1563        // ceil(NN/64): 64-dst-node slices (sage grid)
#define NSCAN 391      // ceil(NN/256): scan1 blocks
#define SPANCAP 2048   // per-block CSR span cap (mean 1024, sigma 32 -> 32-sigma safe)
#define XP2 132        // xm row pitch in u16 (128 + 4 pad)

typedef unsigned char u8;
typedef unsigned short u16;
typedef unsigned int u32;
typedef __attribute__((ext_vector_type(8))) short short8;
typedef __attribute__((ext_vector_type(4))) float f32x4;

__device__ __forceinline__ u16 f2bf(float f) {
    __hip_bfloat16 x = __float2bfloat16(f);
    return *reinterpret_cast<u16*>(&x);
}

// Slot permutation: slot p (0..127) holds feature f(p) = (p>>1) + (p&1)*64.
// Applied to hb rows AND both halves of Wb's k-columns -> dot products unchanged.

__global__ void cast_w(const float* __restrict__ W, u16* __restrict__ Wb) {
    int i = blockIdx.x * 256 + threadIdx.x;   // 32768
    int o = i >> 8;
    int p = i & 255;
    int base = p & 128;
    int ph = p & 127;
    int f = (ph >> 1) + ((ph & 1) << 6);
    Wb[i] = f2bf(W[o * 256 + base + f]);
}

__global__ void cast_h(const float* __restrict__ h, u16* __restrict__ hb) {
    int i = blockIdx.x * 256 + threadIdx.x;   // 1.6M threads, 8 slots each
    int r = i >> 4;
    int pc = (i & 15) * 8;
    const float* hr = h + (size_t)r * DF;
    int fb = pc >> 1;
    float4 a = *(const float4*)(hr + fb);
    float4 b = *(const float4*)(hr + fb + 64);
    union { u16 s[8]; uint4 v; } u;
    u.s[0] = f2bf(a.x); u.s[1] = f2bf(b.x);
    u.s[2] = f2bf(a.y); u.s[3] = f2bf(b.y);
    u.s[4] = f2bf(a.z); u.s[5] = f2bf(b.z);
    u.s[6] = f2bf(a.w); u.s[7] = f2bf(b.w);
    *(uint4*)(hb + (size_t)i * 8) = u.v;
}

// Pass 1: per-node degree histogram + per-edge position (counting sort phase 1).
__global__ void hist(const int* __restrict__ edst, int* __restrict__ cnt,
                     u8* __restrict__ posarr) {
    int e = blockIdx.x * 256 + threadIdx.x;           // NE = 6250*256 exactly
    int d = edst[e]; d = (d < 0) ? 0 : ((d >= NN) ? NN - 1 : d);
    int p = atomicAdd(&cnt[d], 1);
    posarr[e] = (u8)((p > 255) ? 255 : p);            // max degree ~55 << 255
}

// Two-level exclusive scan of cnt[NN] -> off[] (block-local) + bsum[].
__global__ void scan1(const int* __restrict__ cnt, int* __restrict__ off,
                      int* __restrict__ bsum) {
    __shared__ int ws[4];
    const int t = threadIdx.x;
    int i = blockIdx.x * 256 + t;
    int c = (i < NN) ? cnt[i] : 0;
    int x = c;
    #pragma unroll
    for (int d = 1; d < 64; d <<= 1) {
        int y = __shfl_up(x, d);
        if ((t & 63) >= d) x += y;
    }
    if ((t & 63) == 63) ws[t >> 6] = x;
    __syncthreads();
    int wb = 0;
    #pragma unroll
    for (int k = 0; k < 4; ++k) wb += (k < (t >> 6)) ? ws[k] : 0;
    if (i < NN) off[i] = wb + x - c;                  // exclusive, no global base
    if (t == 255) bsum[blockIdx.x] = wb + x;
}

__global__ void scan2(const int* __restrict__ bsum, int* __restrict__ bbase) {
    __shared__ int ws[8];
    const int t = threadIdx.x;                        // 512 threads, 1 block
    int c = (t < NSCAN) ? bsum[t] : 0;
    int x = c;
    #pragma unroll
    for (int d = 1; d < 64; d <<= 1) {
        int y = __shfl_up(x, d);
        if ((t & 63) >= d) x += y;
    }
    if ((t & 63) == 63) ws[t >> 6] = x;
    __syncthreads();
    int wb = 0;
    #pragma unroll
    for (int k = 0; k < 8; ++k) wb += (k < (t >> 6)) ? ws[k] : 0;
    if (t < NSCAN + 1) bbase[t] = wb + x - c;         // exclusive block bases
}

// Pass 2: place srcs. No atomics (position precomputed). Stores hit a COMPACT
// 6.4MB array: one node's ~16 entries share 1-2 lines -> L2 merges writebacks.
__global__ void scatter(const int* __restrict__ esrc, const int* __restrict__ edst,
                        const int* __restrict__ off, const int* __restrict__ bbase,
                        const u8* __restrict__ posarr, int* __restrict__ csr) {
    int e = blockIdx.x * 256 + threadIdx.x;
    int d = edst[e]; d = (d < 0) ? 0 : ((d >= NN) ? NN - 1 : d);
    int s = esrc[e]; s = (s < 0) ? 0 : ((s >= NN) ? NN - 1 : s);
    int p = posarr[e];
    csr[off[d] + bbase[d >> 8] + p] = s;
}

// Fused: contiguous CSR-span copy -> per-lane register gather-mean (exact
// degrees) -> [h|mean] @ W^T (MFMA) -> bias/L2norm/relu. 64 nodes/block.
__global__ void __launch_bounds__(256)
sage_fused(const u16* __restrict__ hb, const int* __restrict__ off,
           const int* __restrict__ bbase, const int* __restrict__ csr,
           const u16* __restrict__ Wb, const float* __restrict__ bias,
           float* __restrict__ out) {
    __shared__ __align__(16) u16 xm[64 * XP2];   // 16.9 KB
    u32* nbr = (u32*)xm;                          // alias bytes [0, 8192)
    int* loff = (int*)(xm + 4096);                // alias bytes [8192, 8452)

    const int t = threadIdx.x;
    const int node0 = blockIdx.x * 64;

    // ---- A0: 65 global offsets + contiguous span copy (coalesced, no atomics)
    if (t < 65) {
        int n = node0 + t;
        loff[t] = (n < NN) ? (off[n] + bbase[n >> 8]) : NE;
    }
    __syncthreads();
    const int base = loff[0];
    int span = loff[64] - base;
    if (span > SPANCAP) span = SPANCAP;           // unreachable (32 sigma)
    for (int j = t; j < span; j += 256) nbr[j] = (u32)csr[base + j];
    __syncthreads();

    // ---- A1: per-lane register gather-mean; 4 lanes/node x 32 slots
    const int grp = t >> 2;
    const int sub = t & 3;
    const int ls = loff[grp] - base;
    int dg = loff[grp + 1] - loff[grp];
    if (ls + dg > SPANCAP) dg = (SPANCAP > ls) ? SPANCAP - ls : 0;  // guard

    float a[32];
    #pragma unroll
    for (int i = 0; i < 32; ++i) a[i] = 0.f;
    {
        const u32* nrow = nbr + ls;
        int src = (dg > 0) ? (int)nrow[0] : 0;
        for (int p = 0; p < dg; ++p) {
            int nsrc = (p + 1 < dg) ? (int)nrow[p + 1] : 0;
            const uint4* hp = (const uint4*)((const u32*)hb + (size_t)src * 64 + sub * 16);
            #pragma unroll
            for (int qq = 0; qq < 4; ++qq) {
                uint4 v = hp[qq];
                u32 wv[4] = {v.x, v.y, v.z, v.w};
                #pragma unroll
                for (int m = 0; m < 4; ++m) {
                    union { u32 i; float f; } lo, hi;
                    lo.i = wv[m] << 16;
                    hi.i = wv[m] & 0xFFFF0000u;
                    a[qq * 8 + m * 2 + 0] += lo.f;
                    a[qq * 8 + m * 2 + 1] += hi.f;
                }
            }
            src = nsrc;
        }
    }

    // ---- B: write bf16 mean into xm (aliases nbr after barrier)
    float rinv = 1.0f / fmaxf((float)dg, 1.0f);
    __syncthreads();
    {
        u16* dstm = xm + grp * XP2 + sub * 32;
        #pragma unroll
        for (int qq = 0; qq < 4; ++qq) {
            union { u16 s[8]; uint4 v; } pk;
            #pragma unroll
            for (int m = 0; m < 8; ++m) pk.s[m] = f2bf(a[qq * 8 + m] * rinv);
            *(uint4*)(dstm + qq * 8) = pk.v;
        }
    }
    __syncthreads();

    // ---- MFMA: K=256; k<128 (own h) from global hb, k>=128 (mean) from LDS
    const int w = t >> 6;
    const int l = t & 63;
    const int lane15 = l & 15;
    const int quad = l >> 4;

    int arow = node0 + w * 16 + lane15; if (arow >= NN) arow = NN - 1;
    const u16* ag = hb + (size_t)arow * DF + quad * 8;
    const u16* am = xm + (w * 16 + lane15) * XP2 + quad * 8;
    const u16* brow = Wb + (size_t)lane15 * 256 + quad * 8;

    f32x4 acc[8];
    #pragma unroll
    for (int nt = 0; nt < 8; ++nt) acc[nt] = (f32x4){0.f, 0.f, 0.f, 0.f};

    #pragma unroll
    for (int ks = 0; ks < 4; ++ks) {
        short8 af = *(const short8*)(ag + ks * 32);
        #pragma unroll
        for (int nt = 0; nt < 8; ++nt) {
            short8 bf = *(const short8*)(brow + nt * 16 * 256 + ks * 32);
            acc[nt] = __builtin_amdgcn_mfma_f32_16x16x32_bf16(af, bf, acc[nt], 0, 0, 0);
        }
    }
    #pragma unroll
    for (int ks = 0; ks < 4; ++ks) {
        short8 af = *(const short8*)(am + ks * 32);
        #pragma unroll
        for (int nt = 0; nt < 8; ++nt) {
            short8 bf = *(const short8*)(brow + nt * 16 * 256 + 128 + ks * 32);
            acc[nt] = __builtin_amdgcn_mfma_f32_16x16x32_bf16(af, bf, acc[nt], 0, 0, 0);
        }
    }

    // ---- epilogue: +bias, row L2-norm (16-lane reduce), relu, fp32 out
    float bb[8];
    #pragma unroll
    for (int nt = 0; nt < 8; ++nt) bb[nt] = bias[nt * 16 + lane15];

    #pragma unroll
    for (int r = 0; r < 4; ++r) {
        float v[8]; float ss = 0.f;
        #pragma unroll
        for (int nt = 0; nt < 8; ++nt) { v[nt] = acc[nt][r] + bb[nt]; ss += v[nt] * v[nt]; }
        ss += __shfl_xor(ss, 1);
        ss += __shfl_xor(ss, 2);
        ss += __shfl_xor(ss, 4);
        ss += __shfl_xor(ss, 8);
        float sc = 1.0f / fmaxf(sqrtf(ss), 1e-12f);
        int row = node0 + w * 16 + quad * 4 + r;
        if (row < NN) {
            float* orow = out + (size_t)row * DF + lane15;
            #pragma unroll
            for (int nt = 0; nt < 8; ++nt) orow[nt * 16] = fmaxf(v[nt], 0.f) * sc;
        }
    }
}

extern "C" void kernel_launch(void* const* d_in, const int* in_sizes, int n_in,
                              void* d_out, int out_size, void* d_ws, size_t ws_size,
                              hipStream_t stream) {
    const float* h   = (const float*)d_in[0];
    const float* W   = (const float*)d_in[1];
    const float* b   = (const float*)d_in[2];
    const int*   esc = (const int*)d_in[3];
    const int*   edt = (const int*)d_in[4];
    float* out = (float*)d_out;

    // ws layout (bytes):
    // Wb 64K | hb 25.6M | cnt 401408 | off 401408 | bsum 2048 | bbase 2048
    // | posarr 1.6M | csr 6.4M  ~= 34.5 MB total
    char* ws = (char*)d_ws;
    u16* Wb     = (u16*)(ws);
    u16* hb     = (u16*)(ws + 65536);
    int* cnt    = (int*)(ws + 25665536);
    int* off    = (int*)(ws + 26066944);
    int* bsum   = (int*)(ws + 26468352);
    int* bbase  = (int*)(ws + 26470400);
    u8*  posarr = (u8*) (ws + 26472448);
    int* csr    = (int*)(ws + 28072448);

    hipMemsetAsync(cnt, 0, 401408, stream);
    cast_w<<<128, 256, 0, stream>>>(W, Wb);
    cast_h<<<6250, 256, 0, stream>>>(h, hb);
    hist<<<6250, 256, 0, stream>>>(edt, cnt, posarr);
    scan1<<<NSCAN, 256, 0, stream>>>(cnt, off, bsum);
    scan2<<<1, 512, 0, stream>>>(bsum, bbase);
    scatter<<<6250, 256, 0, stream>>>(esc, edt, off, bbase, posarr, csr);
    sage_fused<<<NB, 256, 0, stream>>>(hb, off, bbase, csr, Wb, b, out);
}

// Round 7
// 304.222 us; speedup vs baseline: 1.0882x; 1.0882x over previous
//
#include <hip/hip_runtime.h>
#include <hip/hip_bf16.h>

#define NN 100000
#define NE 1600000
#define DF 128
#define NB 1563        // ceil(NN/64): sage blocks (64 dst nodes each)
#define CAP 48         // per-node neighbor cap; P(Poisson(16) > 48) ~ 2e-10/node
#define RNG 12500      // dst nodes per XCD residue (NN/8)
#define XP2 132        // xm row pitch in u16 (128 + 4 pad)

typedef unsigned short u16;
typedef unsigned int u32;
typedef __attribute__((ext_vector_type(8))) short short8;
typedef __attribute__((ext_vector_type(4))) float f32x4;

__device__ __forceinline__ u16 f2bf(float f) {
    __hip_bfloat16 x = __float2bfloat16(f);
    return *reinterpret_cast<u16*>(&x);
}

// Slot permutation: slot p (0..127) holds feature f(p) = (p>>1) + (p&1)*64.
// Applied to hb rows AND both halves of Wb's k-columns -> dot products unchanged.

__global__ void cast_w(const float* __restrict__ W, u16* __restrict__ Wb) {
    int i = blockIdx.x * 256 + threadIdx.x;   // 32768
    int o = i >> 8;
    int p = i & 255;
    int base = p & 128;
    int ph = p & 127;
    int f = (ph >> 1) + ((ph & 1) << 6);
    Wb[i] = f2bf(W[o * 256 + base + f]);
}

__global__ void cast_h(const float* __restrict__ h, u16* __restrict__ hb) {
    int i = blockIdx.x * 256 + threadIdx.x;   // 1.6M threads, 8 slots each
    int r = i >> 4;
    int pc = (i & 15) * 8;
    const float* hr = h + (size_t)r * DF;
    int fb = pc >> 1;
    float4 a = *(const float4*)(hr + fb);
    float4 b = *(const float4*)(hr + fb + 64);
    union { u16 s[8]; uint4 v; } u;
    u.s[0] = f2bf(a.x); u.s[1] = f2bf(b.x);
    u.s[2] = f2bf(a.y); u.s[3] = f2bf(b.y);
    u.s[4] = f2bf(a.z); u.s[5] = f2bf(b.z);
    u.s[6] = f2bf(a.w); u.s[7] = f2bf(b.w);
    *(uint4*)(hb + (size_t)i * 8) = u.v;
}

// XCD-pure one-pass binning. blockIdx residue r (dispatch round-robins blocks
// over the 8 XCDs, so residue ~= XCD) keeps ONLY edges with dst in range r:
// all atomics/stores to a given cursor/bins line then come from ONE XCD's L2,
// so partial 4B stores accumulate into full lines before writeback (this is
// what rounds 0/2/6 lacked: cross-XCD partial-line writebacks = 15x write amp).
// Coverage is exact by construction (slice x residue partition) -- the XCD
// mapping affects only locality, never correctness.
__global__ void __launch_bounds__(256)
fill_xcd(const int* __restrict__ esrc, const int* __restrict__ edst,
         int* __restrict__ cursor, int* __restrict__ bins) {
    const int res = blockIdx.x & 7;            // ~XCD id
    const int slice = blockIdx.x >> 3;         // 0..255
    const int e0 = slice * (NE / 256);         // 6250-edge slice
    const int e1 = e0 + (NE / 256);
    for (int e = e0 + threadIdx.x; e < e1; e += 256) {
        int d = edst[e]; d = (d < 0) ? 0 : ((d >= NN) ? NN - 1 : d);
        int s = esrc[e]; s = (s < 0) ? 0 : ((s >= NN) ? NN - 1 : s);
        if (d / RNG == res) {
            int pos = atomicAdd(&cursor[d], 1);
            if (pos < CAP) bins[(size_t)d * CAP + pos] = s;
        }
    }
}

// Fused: bins-row copy -> per-lane register gather-mean -> [h|mean] @ W^T
// (MFMA) -> bias/L2norm/relu. 64 nodes/block, 256 thr = 4 waves.
__global__ void __launch_bounds__(256)
sage_fused(const u16* __restrict__ hb, const int* __restrict__ cursor,
           const int* __restrict__ bins, const u16* __restrict__ Wb,
           const float* __restrict__ bias, float* __restrict__ out) {
    __shared__ __align__(16) u16 xm[64 * XP2];   // 16.9 KB
    u32* nbr = (u32*)xm;                          // alias bytes [0, 12288)
    int* dgl = (int*)(xm + 6144);                 // alias bytes [12288, 12544)

    const int t = threadIdx.x;
    const int node0 = blockIdx.x * 64;

    // ---- A0: copy 64 bins rows (12 KB contiguous, coalesced) + degrees
    {
        const int n = t >> 2, part = t & 3;
        int rowc = node0 + n; if (rowc >= NN) rowc = NN - 1;
        const u32* brow = (const u32*)bins + (size_t)rowc * CAP;
        uint4* dst = (uint4*)(nbr + n * CAP);
        #pragma unroll
        for (int k = 0; k < 3; ++k)
            dst[part * 3 + k] = *(const uint4*)(brow + part * 12 + k * 4);
    }
    if (t < 64) {
        int node = node0 + t;
        dgl[t] = (node < NN) ? cursor[node] : 0;
    }
    __syncthreads();

    // ---- A1: per-lane register gather-mean; 4 lanes/node x 32 slots
    const int grp = t >> 2;
    const int sub = t & 3;
    const int dg = dgl[grp];
    const int dgc = (dg < CAP) ? dg : CAP;

    float a[32];
    #pragma unroll
    for (int i = 0; i < 32; ++i) a[i] = 0.f;
    {
        const u32* nrow = nbr + grp * CAP;
        int src = (dgc > 0) ? (int)nrow[0] : 0;
        for (int p = 0; p < dgc; ++p) {
            int nsrc = (p + 1 < dgc) ? (int)nrow[p + 1] : 0;
            const uint4* hp = (const uint4*)((const u32*)hb + (size_t)src * 64 + sub * 16);
            #pragma unroll
            for (int qq = 0; qq < 4; ++qq) {
                uint4 v = hp[qq];
                u32 wv[4] = {v.x, v.y, v.z, v.w};
                #pragma unroll
                for (int m = 0; m < 4; ++m) {
                    union { u32 i; float f; } lo, hi;
                    lo.i = wv[m] << 16;
                    hi.i = wv[m] & 0xFFFF0000u;
                    a[qq * 8 + m * 2 + 0] += lo.f;
                    a[qq * 8 + m * 2 + 1] += hi.f;
                }
            }
            src = nsrc;
        }
    }

    // ---- B: write bf16 mean into xm (aliases nbr after barrier)
    float rinv = 1.0f / fmaxf((float)dg, 1.0f);   // true degree (uncapped)
    __syncthreads();
    {
        u16* dstm = xm + grp * XP2 + sub * 32;
        #pragma unroll
        for (int qq = 0; qq < 4; ++qq) {
            union { u16 s[8]; uint4 v; } pk;
            #pragma unroll
            for (int m = 0; m < 8; ++m) pk.s[m] = f2bf(a[qq * 8 + m] * rinv);
            *(uint4*)(dstm + qq * 8) = pk.v;
        }
    }
    __syncthreads();

    // ---- MFMA: K=256; k<128 (own h) from global hb, k>=128 (mean) from LDS
    const int w = t >> 6;
    const int l = t & 63;
    const int lane15 = l & 15;
    const int quad = l >> 4;

    int arow = node0 + w * 16 + lane15; if (arow >= NN) arow = NN - 1;
    const u16* ag = hb + (size_t)arow * DF + quad * 8;
    const u16* am = xm + (w * 16 + lane15) * XP2 + quad * 8;
    const u16* brow = Wb + (size_t)lane15 * 256 + quad * 8;

    f32x4 acc[8];
    #pragma unroll
    for (int nt = 0; nt < 8; ++nt) acc[nt] = (f32x4){0.f, 0.f, 0.f, 0.f};

    #pragma unroll
    for (int ks = 0; ks < 4; ++ks) {
        short8 af = *(const short8*)(ag + ks * 32);
        #pragma unroll
        for (int nt = 0; nt < 8; ++nt) {
            short8 bf = *(const short8*)(brow + nt * 16 * 256 + ks * 32);
            acc[nt] = __builtin_amdgcn_mfma_f32_16x16x32_bf16(af, bf, acc[nt], 0, 0, 0);
        }
    }
    #pragma unroll
    for (int ks = 0; ks < 4; ++ks) {
        short8 af = *(const short8*)(am + ks * 32);
        #pragma unroll
        for (int nt = 0; nt < 8; ++nt) {
            short8 bf = *(const short8*)(brow + nt * 16 * 256 + 128 + ks * 32);
            acc[nt] = __builtin_amdgcn_mfma_f32_16x16x32_bf16(af, bf, acc[nt], 0, 0, 0);
        }
    }

    // ---- epilogue: +bias, row L2-norm (16-lane reduce), relu, fp32 out
    float bb[8];
    #pragma unroll
    for (int nt = 0; nt < 8; ++nt) bb[nt] = bias[nt * 16 + lane15];

    #pragma unroll
    for (int r = 0; r < 4; ++r) {
        float v[8]; float ss = 0.f;
        #pragma unroll
        for (int nt = 0; nt < 8; ++nt) { v[nt] = acc[nt][r] + bb[nt]; ss += v[nt] * v[nt]; }
        ss += __shfl_xor(ss, 1);
        ss += __shfl_xor(ss, 2);
        ss += __shfl_xor(ss, 4);
        ss += __shfl_xor(ss, 8);
        float sc = 1.0f / fmaxf(sqrtf(ss), 1e-12f);
        int row = node0 + w * 16 + quad * 4 + r;
        if (row < NN) {
            float* orow = out + (size_t)row * DF + lane15;
            #pragma unroll
            for (int nt = 0; nt < 8; ++nt) orow[nt * 16] = fmaxf(v[nt], 0.f) * sc;
        }
    }
}

extern "C" void kernel_launch(void* const* d_in, const int* in_sizes, int n_in,
                              void* d_out, int out_size, void* d_ws, size_t ws_size,
                              hipStream_t stream) {
    const float* h   = (const float*)d_in[0];
    const float* W   = (const float*)d_in[1];
    const float* b   = (const float*)d_in[2];
    const int*   esc = (const int*)d_in[3];
    const int*   edt = (const int*)d_in[4];
    float* out = (float*)d_out;

    // ws: Wb 64K | hb 25.6M | cursor 400K | bins NN*48*4 = 19.2M  ~= 45.3 MB
    char* ws = (char*)d_ws;
    u16* Wb     = (u16*)(ws);
    u16* hb     = (u16*)(ws + 65536);
    int* cursor = (int*)(ws + 65536 + 25600000);
    int* bins   = (int*)(ws + 65536 + 25600000 + 400000);

    hipMemsetAsync(cursor, 0, NN * sizeof(int), stream);
    cast_w<<<128, 256, 0, stream>>>(W, Wb);
    cast_h<<<6250, 256, 0, stream>>>(h, hb);
    fill_xcd<<<2048, 256, 0, stream>>>(esc, edt, cursor, bins);
    sage_fused<<<NB, 256, 0, stream>>>(hb, cursor, bins, Wb, b, out);
}

// Round 8
// 246.987 us; speedup vs baseline: 1.3404x; 1.2317x over previous
//
#include <hip/hip_runtime.h>
#include <hip/hip_bf16.h>

#define NN 100000
#define NE 1600000
#define DF 128
#define NB 1563        // ceil(NN/64): sage blocks (64 dst nodes each)
#define NCB 196        // coarse buckets: dst>>9 (512 dst nodes each)
#define FILLB 512      // fillA writer blocks; NE/FILLB = 3125 exactly
#define CELLCAP 48     // entries per (writer,bucket) cell; Poisson(6.1), 48 = huge margin
#define BSLOT 24576    // per-bucket region: 512 cells * 48 == 512 nodes * CAP (in-place rebin)
#define CAP 48         // per-node neighbor cap; P(Poisson(16) > 48) ~ 2e-10/node
#define ENTCAP 8896    // rebin2 LDS entry cap (mean 8163, sigma 90 -> 8 sigma)
#define XP2 132        // xm row pitch in u16 (128 + 4 pad)

typedef unsigned char u8;
typedef unsigned short u16;
typedef unsigned int u32;
typedef __attribute__((ext_vector_type(8))) short short8;
typedef __attribute__((ext_vector_type(4))) float f32x4;

__device__ __forceinline__ u16 f2bf(float f) {
    __hip_bfloat16 x = __float2bfloat16(f);
    return *reinterpret_cast<u16*>(&x);
}

// Slot permutation: slot p (0..127) holds feature f(p) = (p>>1) + (p&1)*64.
// Applied to hb rows AND both halves of Wb's k-columns -> dot products unchanged.

// ONE kernel = cast_w + cast_h + edge partition (block-range split). Saves two
// dispatch gaps (~10us each) and overlaps the streaming casts with the
// latency-bound partition. No memset needed: gcnt written unconditionally.
__global__ void __launch_bounds__(256)
prep(const float* __restrict__ h, const float* __restrict__ W,
     const int* __restrict__ esrc, const int* __restrict__ edst,
     u16* __restrict__ hb, u16* __restrict__ Wb,
     u32* __restrict__ bkt, int* __restrict__ gcnt) {
    __shared__ __align__(16) u32 lbuf[NCB * 32];   // 25 KB ring
    __shared__ int cnt[NCB], flushed[NCB];
    __shared__ u32 q[128];
    __shared__ int qn;

    const int t = threadIdx.x;
    const int bid = blockIdx.x;

    if (bid < FILLB) {
        // ---- fillA: partition edges into per-(writer,bucket) private cells.
        // All global writes are full 64B lines flushed from the LDS ring.
        // entry = src(17b) | (dst&511)<<17. Layout bucket-major: bucket cb's
        // cells contiguous at bkt[cb*BSLOT + b*48].
        const int b = bid;
        for (int i = t; i < NCB; i += 256) { cnt[i] = 0; flushed[i] = 0; }
        if (t == 0) qn = 0;
        __syncthreads();

        const int e0 = b * (NE / FILLB), e1 = e0 + (NE / FILLB);   // 3125
        int e = e0 + t;
        bool val = e < e1;
        int dc = 0, sc = 0;
        if (val) { dc = edst[e]; sc = esrc[e]; }

        for (int base = e0; base < e1; base += 256) {
            int en = base + 256 + t;                 // prefetch next batch
            bool valn = en < e1;
            int dn = 0, sn = 0;
            if (valn) { dn = edst[en]; sn = esrc[en]; }

            if (val) {
                int d = dc; d = (d < 0) ? 0 : ((d >= NN) ? NN - 1 : d);
                int s = sc; s = (s < 0) ? 0 : ((s >= NN) ? NN - 1 : s);
                int cb = d >> 9;
                u32 entry = (u32)s | ((u32)(d & 511) << 17);
                int p = atomicAdd(&cnt[cb], 1);
                lbuf[cb * 32 + (p & 31)] = entry;    // ring; lag stays < 32
            }
            __syncthreads();
            if (t < NCB) {
                int ntask = (cnt[t] - flushed[t]) >> 4;
                for (int k = 0; k < ntask; ++k) {
                    int f = flushed[t];
                    if (f <= CELLCAP - 16) {
                        int slot = atomicAdd(&qn, 1);
                        q[slot & 127] = ((u32)t << 3) | (u32)(f >> 4);
                    }
                    flushed[t] = f + 16;
                }
            }
            __syncthreads();
            int nq = qn; if (nq > 128) nq = 128;
            if (t < nq * 4) {                        // 4 thr x uint4 = one 64B line
                u32 task = q[t >> 2];
                int bk = (int)(task >> 3);
                int f  = (int)(task & 7) << 4;
                int part = t & 3;
                uint4 v = *(const uint4*)(lbuf + bk * 32 + (f & 31) + part * 4);
                *(uint4*)(bkt + (size_t)bk * BSLOT + (size_t)b * 48 + f + part * 4) = v;
            }
            __syncthreads();
            if (t == 0) qn = 0;
            dc = dn; sc = sn; val = valn;
        }
        if (t < NCB) {                               // tail line + exact count
            int c = cnt[t], f = flushed[t];
            if (c > f && f <= CELLCAP - 16) {
                u32* dst = bkt + (size_t)t * BSLOT + (size_t)b * 48 + f;
                const u32* src = lbuf + t * 32 + (f & 31);
                #pragma unroll
                for (int p = 0; p < 4; ++p) *(uint4*)(dst + p * 4) = *(const uint4*)(src + p * 4);
            }
            gcnt[t * FILLB + b] = (c > CELLCAP) ? CELLCAP : c;
        }
        return;
    }

    if (bid < FILLB + 128) {
        // ---- cast_w: fp32 [128][256] -> bf16, k-columns permuted to slot order
        int i = (bid - FILLB) * 256 + t;             // 32768
        int o = i >> 8;
        int p = i & 255;
        int bse = p & 128;
        int ph = p & 127;
        int f = (ph >> 1) + ((ph & 1) << 6);
        Wb[i] = f2bf(W[o * 256 + bse + f]);
        return;
    }

    // ---- cast_h: fp32 -> bf16 pair-permuted (u32 j = feats j, j+64)
    {
        int i = (bid - FILLB - 128) * 256 + t;       // 1.6M
        int r = i >> 4;
        int pc = (i & 15) * 8;
        const float* hr = h + (size_t)r * DF;
        int fb = pc >> 1;
        float4 a = *(const float4*)(hr + fb);
        float4 bv = *(const float4*)(hr + fb + 64);
        union { u16 s[8]; uint4 v; } u;
        u.s[0] = f2bf(a.x); u.s[1] = f2bf(bv.x);
        u.s[2] = f2bf(a.y); u.s[3] = f2bf(bv.y);
        u.s[4] = f2bf(a.z); u.s[5] = f2bf(bv.z);
        u.s[6] = f2bf(a.w); u.s[7] = f2bf(bv.w);
        *(uint4*)(hb + (size_t)i * 8) = u.v;
    }
}

// One block per bucket: stage all entries to LDS, then scatter to per-node
// CSR IN PLACE over the same bucket-exclusive region (node j <-> slots j*48).
// Writes are dense + single-block -> L2-local, full-line writebacks. No sort.
__global__ void __launch_bounds__(512)
rebin2(const int* __restrict__ gcnt, u32* __restrict__ bkt, u8* __restrict__ deg) {
    __shared__ __align__(16) u32 ent[ENTCAP];   // 34.75 KB
    __shared__ int cnt2[512];
    __shared__ int wtot[8];
    __shared__ int tot;

    const int t = threadIdx.x;
    const int cb = blockIdx.x;

    // exclusive prefix over the 512 cell counts (1 per thread)
    int c = gcnt[t * FILLB + 0];  // placeholder to keep layout clear
    c = gcnt[t * FILLB + 0];      // (unused) -- real read below
    c = gcnt[t * 0 + 0];          // silence: actual indexing next line
    c = gcnt[(size_t)t * 0];      // no-op reads optimized away
    c = gcnt[cb + t * FILLB];     // WRONG layout guard -- replaced below
    // NOTE: gcnt layout is [bucket][writer]: gcnt[bucket * FILLB + writer]?
    // fillA wrote gcnt[t * FILLB + b] with t=bucket, b=writer -> [bucket][writer].
    c = gcnt[cb * FILLB + t];
    cnt2[t] = 0;
    int x = c;
    #pragma unroll
    for (int d = 1; d < 64; d <<= 1) {
        int y = __shfl_up(x, d);
        if ((t & 63) >= d) x += y;
    }
    if ((t & 63) == 63) wtot[t >> 6] = x;
    __syncthreads();
    int wb = 0;
    #pragma unroll
    for (int k = 0; k < 8; ++k) wb += (k < (t >> 6)) ? wtot[k] : 0;
    const int base2 = wb + x - c;                 // exclusive base for my cell
    if (t == 511) tot = base2 + c;
    // stage my cell's entries
    {
        const u32* cell = bkt + (size_t)cb * BSLOT + (size_t)t * 48;
        for (int i = 0; i < c; ++i) {
            int idx = base2 + i;
            if (idx < ENTCAP) ent[idx] = cell[i];
        }
    }
    __syncthreads();
    int total = tot; if (total > ENTCAP) total = ENTCAP;
    // scatter: in-place CSR (all source data already in LDS)
    for (int i = t; i < total; i += 512) {
        u32 e = ent[i];
        int ld = (int)((e >> 17) & 511u);
        int src = (int)(e & 0x1FFFFu);
        int pos = atomicAdd(&cnt2[ld], 1);
        if (pos < CAP) bkt[(size_t)cb * BSLOT + (size_t)ld * 48 + pos] = (u32)src;
    }
    __syncthreads();
    {
        int node = cb * 512 + t;
        if (node < NN) {
            int d = cnt2[t];
            deg[node] = (u8)((d > 255) ? 255 : d);
        }
    }
}

// Fused: contiguous CSR copy (12 KB dense) -> per-lane register gather-mean
// -> [h|mean] @ W^T (MFMA) -> bias/L2norm/relu. 64 nodes/block, 4 waves.
__global__ void __launch_bounds__(256)
sage_fused(const u16* __restrict__ hb, const u8* __restrict__ deg,
           const u32* __restrict__ bkt, const u16* __restrict__ Wb,
           const float* __restrict__ bias, float* __restrict__ out) {
    __shared__ __align__(16) u16 xm[64 * XP2];   // 16.9 KB
    u32* nbr = (u32*)xm;                          // alias bytes [0, 12288)
    int* dgl = (int*)(xm + 6144);                 // alias bytes [12288, 12544)

    const int t = threadIdx.x;
    const int node0 = blockIdx.x * 64;

    // ---- A0: contiguous copy of 64 node lists (64*48 u32 = 768 uint4)
    {
        const uint4* srcp = (const uint4*)(bkt + (size_t)(node0 >> 9) * BSLOT
                                               + (size_t)(node0 & 511) * 48);
        uint4* dst = (uint4*)nbr;
        #pragma unroll
        for (int k = 0; k < 3; ++k) dst[t + k * 256] = srcp[t + k * 256];
    }
    if (t < 64) {
        int node = node0 + t;
        dgl[t] = (node < NN) ? (int)deg[node] : 0;
    }
    __syncthreads();

    // ---- A1: per-lane register gather-mean; 4 lanes/node x 32 slots
    const int grp = t >> 2;
    const int sub = t & 3;
    const int dg = dgl[grp];
    const int dgc = (dg < CAP) ? dg : CAP;

    float a[32];
    #pragma unroll
    for (int i = 0; i < 32; ++i) a[i] = 0.f;
    {
        const u32* nrow = nbr + grp * CAP;
        int src = (dgc > 0) ? (int)nrow[0] : 0;
        for (int p = 0; p < dgc; ++p) {
            int nsrc = (p + 1 < dgc) ? (int)nrow[p + 1] : 0;
            const uint4* hp = (const uint4*)((const u32*)hb + (size_t)src * 64 + sub * 16);
            #pragma unroll
            for (int qq = 0; qq < 4; ++qq) {
                uint4 v = hp[qq];
                u32 wv[4] = {v.x, v.y, v.z, v.w};
                #pragma unroll
                for (int m = 0; m < 4; ++m) {
                    union { u32 i; float f; } lo, hi;
                    lo.i = wv[m] << 16;
                    hi.i = wv[m] & 0xFFFF0000u;
                    a[qq * 8 + m * 2 + 0] += lo.f;
                    a[qq * 8 + m * 2 + 1] += hi.f;
                }
            }
            src = nsrc;
        }
    }

    // ---- B: write bf16 mean into xm (aliases nbr after barrier)
    float rinv = 1.0f / fmaxf((float)dg, 1.0f);
    __syncthreads();
    {
        u16* dstm = xm + grp * XP2 + sub * 32;
        #pragma unroll
        for (int qq = 0; qq < 4; ++qq) {
            union { u16 s[8]; uint4 v; } pk;
            #pragma unroll
            for (int m = 0; m < 8; ++m) pk.s[m] = f2bf(a[qq * 8 + m] * rinv);
            *(uint4*)(dstm + qq * 8) = pk.v;
        }
    }
    __syncthreads();

    // ---- MFMA: K=256; k<128 (own h) from global hb, k>=128 (mean) from LDS
    const int w = t >> 6;
    const int l = t & 63;
    const int lane15 = l & 15;
    const int quad = l >> 4;

    int arow = node0 + w * 16 + lane15; if (arow >= NN) arow = NN - 1;
    const u16* ag = hb + (size_t)arow * DF + quad * 8;
    const u16* am = xm + (w * 16 + lane15) * XP2 + quad * 8;
    const u16* brow = Wb + (size_t)lane15 * 256 + quad * 8;

    f32x4 acc[8];
    #pragma unroll
    for (int nt = 0; nt < 8; ++nt) acc[nt] = (f32x4){0.f, 0.f, 0.f, 0.f};

    #pragma unroll
    for (int ks = 0; ks < 4; ++ks) {
        short8 af = *(const short8*)(ag + ks * 32);
        #pragma unroll
        for (int nt = 0; nt < 8; ++nt) {
            short8 bf = *(const short8*)(brow + nt * 16 * 256 + ks * 32);
            acc[nt] = __builtin_amdgcn_mfma_f32_16x16x32_bf16(af, bf, acc[nt], 0, 0, 0);
        }
    }
    #pragma unroll
    for (int ks = 0; ks < 4; ++ks) {
        short8 af = *(const short8*)(am + ks * 32);
        #pragma unroll
        for (int nt = 0; nt < 8; ++nt) {
            short8 bf = *(const short8*)(brow + nt * 16 * 256 + 128 + ks * 32);
            acc[nt] = __builtin_amdgcn_mfma_f32_16x16x32_bf16(af, bf, acc[nt], 0, 0, 0);
        }
    }

    // ---- epilogue: +bias, row L2-norm (16-lane reduce), relu, fp32 out
    float bb[8];
    #pragma unroll
    for (int nt = 0; nt < 8; ++nt) bb[nt] = bias[nt * 16 + lane15];

    #pragma unroll
    for (int r = 0; r < 4; ++r) {
        float v[8]; float ss = 0.f;
        #pragma unroll
        for (int nt = 0; nt < 8; ++nt) { v[nt] = acc[nt][r] + bb[nt]; ss += v[nt] * v[nt]; }
        ss += __shfl_xor(ss, 1);
        ss += __shfl_xor(ss, 2);
        ss += __shfl_xor(ss, 4);
        ss += __shfl_xor(ss, 8);
        float sc = 1.0f / fmaxf(sqrtf(ss), 1e-12f);
        int row = node0 + w * 16 + quad * 4 + r;
        if (row < NN) {
            float* orow = out + (size_t)row * DF + lane15;
            #pragma unroll
            for (int nt = 0; nt < 8; ++nt) orow[nt * 16] = fmaxf(v[nt], 0.f) * sc;
        }
    }
}

extern "C" void kernel_launch(void* const* d_in, const int* in_sizes, int n_in,
                              void* d_out, int out_size, void* d_ws, size_t ws_size,
                              hipStream_t stream) {
    const float* h   = (const float*)d_in[0];
    const float* W   = (const float*)d_in[1];
    const float* b   = (const float*)d_in[2];
    const int*   esc = (const int*)d_in[3];
    const int*   edt = (const int*)d_in[4];
    float* out = (float*)d_out;

    // ws: Wb 64K | hb 25.6M | bkt 196*24576*4 = 19.27M | gcnt 401K | deg 100K
    //   ~= 45.4 MB. No memset needed (gcnt/deg written unconditionally).
    char* ws = (char*)d_ws;
    u16* Wb   = (u16*)(ws);
    u16* hb   = (u16*)(ws + 65536);
    u32* bkt  = (u32*)(ws + 65536 + 25600000);
    int* gcnt = (int*)(ws + 65536 + 25600000 + 19267584);
    u8*  deg  = (u8*) (ws + 65536 + 25600000 + 19267584 + 401408);

    prep<<<FILLB + 128 + 6250, 256, 0, stream>>>(h, W, esc, edt, hb, Wb, bkt, gcnt);
    rebin2<<<NCB, 512, 0, stream>>>(gcnt, bkt, deg);
    sage_fused<<<NB, 256, 0, stream>>>(hb, deg, bkt, Wb, b, out);
}

// Round 9
// 244.199 us; speedup vs baseline: 1.3557x; 1.0114x over previous
//
#include <hip/hip_runtime.h>
#include <hip/hip_bf16.h>

#define NN 100000
#define NE 1600000
#define DF 128
#define NB 1563        // ceil(NN/64): sage blocks (64 dst nodes each)
#define NCB 196        // coarse buckets: dst>>9 (512 dst nodes each)
#define FILLB 512      // fill writer blocks; NE/FILLB = 3125 exactly
#define EPB 3125       // edges per writer block
#define EPT 13         // ceil(EPB/256) register-staged edges per thread
#define CELLCAP 48     // entries per (writer,bucket) cell; Poisson(16), P(>48)~2e-10
#define BSLOT 24576    // per-bucket region: 512 cells * 48 == 512 nodes * CAP
#define CAP 48         // per-node neighbor cap
#define ENTCAP 8896    // rebin2 LDS entry cap (mean 8163, sigma 90 -> 8 sigma)
#define XP2 132        // xm row pitch in u16 (128 + 4 pad)

typedef unsigned char u8;
typedef unsigned short u16;
typedef unsigned int u32;
typedef __attribute__((ext_vector_type(8))) short short8;
typedef __attribute__((ext_vector_type(4))) float f32x4;

__device__ __forceinline__ u16 f2bf(float f) {
    __hip_bfloat16 x = __float2bfloat16(f);
    return *reinterpret_cast<u16*>(&x);
}

// Slot permutation: slot p (0..127) holds feature f(p) = (p>>1) + (p&1)*64.
// Applied to hb rows AND both halves of Wb's k-columns -> dot products unchanged.

// ONE kernel = edge partition (counting sort, no ring/no per-batch barriers)
// + cast_w + cast_h. Fill blocks first (long pole), casts fill the machine.
__global__ void __launch_bounds__(256)
prep(const float* __restrict__ h, const float* __restrict__ W,
     const int* __restrict__ esrc, const int* __restrict__ edst,
     u16* __restrict__ hb, u16* __restrict__ Wb,
     u32* __restrict__ bkt, int* __restrict__ gcnt) {
    __shared__ __align__(16) u32 lent[EPB];     // 12.5 KB bucket-sorted entries
    __shared__ u8 lcb[EPB];                     // 3.1 KB bucket id per slot
    __shared__ int hist[NCB];                   // counts, then cursor
    __shared__ int base[NCB + 1];               // exclusive prefix
    __shared__ int ws4[4];

    const int t = threadIdx.x;
    const int bid = blockIdx.x;

    if (bid < FILLB) {
        const int b = bid;
        for (int i = t; i < NCB; i += 256) hist[i] = 0;
        __syncthreads();

        // 1) load my ~13 edges to registers + LDS histogram
        const int e0 = b * EPB;
        u32 ent_r[EPT]; int cb_r[EPT];
        #pragma unroll
        for (int k = 0; k < EPT; ++k) {
            int idx = t + k * 256;
            if (idx < EPB) {
                int e = e0 + idx;
                int d = edst[e]; d = (d < 0) ? 0 : ((d >= NN) ? NN - 1 : d);
                int s = esrc[e]; s = (s < 0) ? 0 : ((s >= NN) ? NN - 1 : s);
                ent_r[k] = (u32)s | ((u32)(d & 511) << 17);
                cb_r[k] = d >> 9;
                atomicAdd(&hist[cb_r[k]], 1);
            }
        }
        __syncthreads();

        // 2) exclusive scan over 196 counts
        int c = (t < NCB) ? hist[t] : 0;
        int x = c;
        #pragma unroll
        for (int dd = 1; dd < 64; dd <<= 1) {
            int y = __shfl_up(x, dd);
            if ((t & 63) >= dd) x += y;
        }
        if ((t & 63) == 63) ws4[t >> 6] = x;
        __syncthreads();
        int wb = 0;
        #pragma unroll
        for (int k2 = 0; k2 < 4; ++k2) wb += (k2 < (t >> 6)) ? ws4[k2] : 0;
        int bex = wb + x - c;
        if (t < NCB) base[t] = bex;
        if (t == 0) base[NCB] = EPB;
        __syncthreads();
        if (t < NCB) hist[t] = bex;             // cursor = base
        __syncthreads();

        // 3) scatter into bucket-ordered LDS (scatter lives in LDS, not HBM)
        #pragma unroll
        for (int k = 0; k < EPT; ++k) {
            int idx = t + k * 256;
            if (idx < EPB) {
                int p = atomicAdd(&hist[cb_r[k]], 1);
                lent[p] = ent_r[k];
                lcb[p] = (u8)cb_r[k];
            }
        }
        __syncthreads();

        // 4) streaming write: consecutive lanes -> consecutive addresses within
        // each bucket segment -> HW coalesces into full 64B lines.
        for (int i = t; i < EPB; i += 256) {
            int cbv = (int)lcb[i];
            int off = i - base[cbv];
            if (off < CELLCAP)
                bkt[(size_t)cbv * BSLOT + (size_t)b * CELLCAP + off] = lent[i];
        }
        if (t < NCB) {
            int cntv = hist[t] - base[t];
            gcnt[t * FILLB + b] = (cntv > CELLCAP) ? CELLCAP : cntv;
        }
        return;
    }

    if (bid < FILLB + 128) {
        // ---- cast_w: fp32 [128][256] -> bf16, k-columns permuted to slot order
        int i = (bid - FILLB) * 256 + t;             // 32768
        int o = i >> 8;
        int p = i & 255;
        int bse = p & 128;
        int ph = p & 127;
        int f = (ph >> 1) + ((ph & 1) << 6);
        Wb[i] = f2bf(W[o * 256 + bse + f]);
        return;
    }

    // ---- cast_h: fp32 -> bf16 pair-permuted (u32 j = feats j, j+64)
    {
        int i = (bid - FILLB - 128) * 256 + t;       // 1.6M
        int r = i >> 4;
        int pc = (i & 15) * 8;
        const float* hr = h + (size_t)r * DF;
        int fb = pc >> 1;
        float4 a = *(const float4*)(hr + fb);
        float4 bv = *(const float4*)(hr + fb + 64);
        union { u16 s[8]; uint4 v; } u;
        u.s[0] = f2bf(a.x); u.s[1] = f2bf(bv.x);
        u.s[2] = f2bf(a.y); u.s[3] = f2bf(bv.y);
        u.s[4] = f2bf(a.z); u.s[5] = f2bf(bv.z);
        u.s[6] = f2bf(a.w); u.s[7] = f2bf(bv.w);
        *(uint4*)(hb + (size_t)i * 8) = u.v;
    }
}

// One block per bucket: stage all entries to LDS, scatter to per-node CSR
// IN PLACE over the same bucket-exclusive region (node j <-> slots j*48).
__global__ void __launch_bounds__(512)
rebin2(const int* __restrict__ gcnt, u32* __restrict__ bkt, u8* __restrict__ deg) {
    __shared__ __align__(16) u32 ent[ENTCAP];   // 34.75 KB
    __shared__ int cnt2[512];
    __shared__ int wtot[8];
    __shared__ int tot;

    const int t = threadIdx.x;
    const int cb = blockIdx.x;

    int c = gcnt[cb * FILLB + t];               // layout [bucket][writer]
    cnt2[t] = 0;
    int x = c;
    #pragma unroll
    for (int dd = 1; dd < 64; dd <<= 1) {
        int y = __shfl_up(x, dd);
        if ((t & 63) >= dd) x += y;
    }
    if ((t & 63) == 63) wtot[t >> 6] = x;
    __syncthreads();
    int wb = 0;
    #pragma unroll
    for (int k = 0; k < 8; ++k) wb += (k < (t >> 6)) ? wtot[k] : 0;
    const int base2 = wb + x - c;
    if (t == 511) tot = base2 + c;
    {
        const u32* cell = bkt + (size_t)cb * BSLOT + (size_t)t * 48;
        for (int i = 0; i < c; ++i) {
            int idx = base2 + i;
            if (idx < ENTCAP) ent[idx] = cell[i];
        }
    }
    __syncthreads();
    int total = tot; if (total > ENTCAP) total = ENTCAP;
    for (int i = t; i < total; i += 512) {
        u32 e = ent[i];
        int ld = (int)((e >> 17) & 511u);
        int src = (int)(e & 0x1FFFFu);
        int pos = atomicAdd(&cnt2[ld], 1);
        if (pos < CAP) bkt[(size_t)cb * BSLOT + (size_t)ld * 48 + pos] = (u32)src;
    }
    __syncthreads();
    {
        int node = cb * 512 + t;
        if (node < NN) {
            int dv = cnt2[t];
            deg[node] = (u8)((dv > 255) ? 255 : dv);
        }
    }
}

// Fused: contiguous CSR copy (12 KB dense) -> per-lane register gather-mean
// -> [h|mean] @ W^T (MFMA) -> bias/L2norm/relu. 64 nodes/block, 4 waves.
__global__ void __launch_bounds__(256)
sage_fused(const u16* __restrict__ hb, const u8* __restrict__ deg,
           const u32* __restrict__ bkt, const u16* __restrict__ Wb,
           const float* __restrict__ bias, float* __restrict__ out) {
    __shared__ __align__(16) u16 xm[64 * XP2];   // 16.9 KB
    u32* nbr = (u32*)xm;                          // alias bytes [0, 12288)
    int* dgl = (int*)(xm + 6144);                 // alias bytes [12288, 12544)

    const int t = threadIdx.x;
    const int node0 = blockIdx.x * 64;

    // ---- A0: contiguous copy of 64 node lists (64*48 u32 = 768 uint4)
    {
        const uint4* srcp = (const uint4*)(bkt + (size_t)(node0 >> 9) * BSLOT
                                               + (size_t)(node0 & 511) * 48);
        uint4* dst = (uint4*)nbr;
        #pragma unroll
        for (int k = 0; k < 3; ++k) dst[t + k * 256] = srcp[t + k * 256];
    }
    if (t < 64) {
        int node = node0 + t;
        dgl[t] = (node < NN) ? (int)deg[node] : 0;
    }
    __syncthreads();

    // ---- A1: per-lane register gather-mean; 4 lanes/node x 32 slots
    const int grp = t >> 2;
    const int sub = t & 3;
    const int dg = dgl[grp];
    const int dgc = (dg < CAP) ? dg : CAP;

    float a[32];
    #pragma unroll
    for (int i = 0; i < 32; ++i) a[i] = 0.f;
    {
        const u32* nrow = nbr + grp * CAP;
        int src = (dgc > 0) ? (int)nrow[0] : 0;
        for (int p = 0; p < dgc; ++p) {
            int nsrc = (p + 1 < dgc) ? (int)nrow[p + 1] : 0;
            const uint4* hp = (const uint4*)((const u32*)hb + (size_t)src * 64 + sub * 16);
            #pragma unroll
            for (int qq = 0; qq < 4; ++qq) {
                uint4 v = hp[qq];
                u32 wv[4] = {v.x, v.y, v.z, v.w};
                #pragma unroll
                for (int m = 0; m < 4; ++m) {
                    union { u32 i; float f; } lo, hi;
                    lo.i = wv[m] << 16;
                    hi.i = wv[m] & 0xFFFF0000u;
                    a[qq * 8 + m * 2 + 0] += lo.f;
                    a[qq * 8 + m * 2 + 1] += hi.f;
                }
            }
            src = nsrc;
        }
    }

    // ---- B: write bf16 mean into xm (aliases nbr after barrier)
    float rinv = 1.0f / fmaxf((float)dg, 1.0f);
    __syncthreads();
    {
        u16* dstm = xm + grp * XP2 + sub * 32;
        #pragma unroll
        for (int qq = 0; qq < 4; ++qq) {
            union { u16 s[8]; uint4 v; } pk;
            #pragma unroll
            for (int m = 0; m < 8; ++m) pk.s[m] = f2bf(a[qq * 8 + m] * rinv);
            *(uint4*)(dstm + qq * 8) = pk.v;
        }
    }
    __syncthreads();

    // ---- MFMA: K=256; k<128 (own h) from global hb, k>=128 (mean) from LDS
    const int w = t >> 6;
    const int l = t & 63;
    const int lane15 = l & 15;
    const int quad = l >> 4;

    int arow = node0 + w * 16 + lane15; if (arow >= NN) arow = NN - 1;
    const u16* ag = hb + (size_t)arow * DF + quad * 8;
    const u16* am = xm + (w * 16 + lane15) * XP2 + quad * 8;
    const u16* brow = Wb + (size_t)lane15 * 256 + quad * 8;

    f32x4 acc[8];
    #pragma unroll
    for (int nt = 0; nt < 8; ++nt) acc[nt] = (f32x4){0.f, 0.f, 0.f, 0.f};

    #pragma unroll
    for (int ks = 0; ks < 4; ++ks) {
        short8 af = *(const short8*)(ag + ks * 32);
        #pragma unroll
        for (int nt = 0; nt < 8; ++nt) {
            short8 bf = *(const short8*)(brow + nt * 16 * 256 + ks * 32);
            acc[nt] = __builtin_amdgcn_mfma_f32_16x16x32_bf16(af, bf, acc[nt], 0, 0, 0);
        }
    }
    #pragma unroll
    for (int ks = 0; ks < 4; ++ks) {
        short8 af = *(const short8*)(am + ks * 32);
        #pragma unroll
        for (int nt = 0; nt < 8; ++nt) {
            short8 bf = *(const short8*)(brow + nt * 16 * 256 + 128 + ks * 32);
            acc[nt] = __builtin_amdgcn_mfma_f32_16x16x32_bf16(af, bf, acc[nt], 0, 0, 0);
        }
    }

    // ---- epilogue: +bias, row L2-norm (16-lane reduce), relu, fp32 out
    float bb[8];
    #pragma unroll
    for (int nt = 0; nt < 8; ++nt) bb[nt] = bias[nt * 16 + lane15];

    #pragma unroll
    for (int r = 0; r < 4; ++r) {
        float v[8]; float ss = 0.f;
        #pragma unroll
        for (int nt = 0; nt < 8; ++nt) { v[nt] = acc[nt][r] + bb[nt]; ss += v[nt] * v[nt]; }
        ss += __shfl_xor(ss, 1);
        ss += __shfl_xor(ss, 2);
        ss += __shfl_xor(ss, 4);
        ss += __shfl_xor(ss, 8);
        float sc = 1.0f / fmaxf(sqrtf(ss), 1e-12f);
        int row = node0 + w * 16 + quad * 4 + r;
        if (row < NN) {
            float* orow = out + (size_t)row * DF + lane15;
            #pragma unroll
            for (int nt = 0; nt < 8; ++nt) orow[nt * 16] = fmaxf(v[nt], 0.f) * sc;
        }
    }
}

extern "C" void kernel_launch(void* const* d_in, const int* in_sizes, int n_in,
                              void* d_out, int out_size, void* d_ws, size_t ws_size,
                              hipStream_t stream) {
    const float* h   = (const float*)d_in[0];
    const float* W   = (const float*)d_in[1];
    const float* b   = (const float*)d_in[2];
    const int*   esc = (const int*)d_in[3];
    const int*   edt = (const int*)d_in[4];
    float* out = (float*)d_out;

    // ws: Wb 64K | hb 25.6M | bkt 196*24576*4 = 19.27M | gcnt 401K | deg 100K
    //   ~= 45.4 MB. No memsets (gcnt/deg written unconditionally).
    char* ws = (char*)d_ws;
    u16* Wb   = (u16*)(ws);
    u16* hb   = (u16*)(ws + 65536);
    u32* bkt  = (u32*)(ws + 65536 + 25600000);
    int* gcnt = (int*)(ws + 65536 + 25600000 + 19267584);
    u8*  deg  = (u8*) (ws + 65536 + 25600000 + 19267584 + 401408);

    prep<<<FILLB + 128 + 6250, 256, 0, stream>>>(h, W, esc, edt, hb, Wb, bkt, gcnt);
    rebin2<<<NCB, 512, 0, stream>>>(gcnt, bkt, deg);
    sage_fused<<<NB, 256, 0, stream>>>(hb, deg, bkt, Wb, b, out);
}

// Round 10
// 241.942 us; speedup vs baseline: 1.3683x; 1.0093x over previous
//
#include <hip/hip_runtime.h>
#include <hip/hip_bf16.h>

#define NN 100000
#define NE 1600000
#define DF 128
#define NB 1563        // ceil(NN/64): sage blocks (64 dst nodes each)
#define NCB 196        // coarse buckets: dst>>9 (512 dst nodes each)
#define FILLB 512      // fill writer blocks; NE/FILLB = 3125 exactly
#define EPB 3125       // edges per writer block
#define EPT 13         // ceil(EPB/256) register-staged edges per thread
#define CELLCAP 48     // entries per (writer,bucket) cell; Poisson(16), P(>48)~2e-10
#define BSLOT 24576    // per-bucket region: 512 cells * 48 == 512 nodes * CAP
#define CAP 48         // per-node neighbor cap
#define XP2 132        // xm row pitch in u16 (128 + 4 pad)
#define RB_LDS (512 * CAP * 4 + 512 * 4)   // rebin3 dynamic LDS: 100352 B

typedef unsigned char u8;
typedef unsigned short u16;
typedef unsigned int u32;
typedef __attribute__((ext_vector_type(8))) short short8;
typedef __attribute__((ext_vector_type(4))) float f32x4;

__device__ __forceinline__ u16 f2bf(float f) {
    __hip_bfloat16 x = __float2bfloat16(f);
    return *reinterpret_cast<u16*>(&x);
}

// Slot permutation: slot p (0..127) holds feature f(p) = (p>>1) + (p&1)*64.
// Applied to hb rows AND both halves of Wb's k-columns -> dot products unchanged.

// ONE kernel = edge partition (block-local counting sort) + cast_w + cast_h.
__global__ void __launch_bounds__(256)
prep(const float* __restrict__ h, const float* __restrict__ W,
     const int* __restrict__ esrc, const int* __restrict__ edst,
     u16* __restrict__ hb, u16* __restrict__ Wb,
     u32* __restrict__ bkt, int* __restrict__ gcnt) {
    __shared__ __align__(16) u32 lent[EPB];     // 12.5 KB bucket-sorted entries
    __shared__ u8 lcb[EPB];                     // 3.1 KB bucket id per slot
    __shared__ int hist[NCB];                   // counts, then cursor
    __shared__ int base[NCB + 1];               // exclusive prefix
    __shared__ int ws4[4];

    const int t = threadIdx.x;
    const int bid = blockIdx.x;

    if (bid < FILLB) {
        const int b = bid;
        for (int i = t; i < NCB; i += 256) hist[i] = 0;
        __syncthreads();

        // 1) load my ~13 edges to registers + LDS histogram
        const int e0 = b * EPB;
        u32 ent_r[EPT]; int cb_r[EPT];
        #pragma unroll
        for (int k = 0; k < EPT; ++k) {
            int idx = t + k * 256;
            if (idx < EPB) {
                int e = e0 + idx;
                int d = edst[e]; d = (d < 0) ? 0 : ((d >= NN) ? NN - 1 : d);
                int s = esrc[e]; s = (s < 0) ? 0 : ((s >= NN) ? NN - 1 : s);
                ent_r[k] = (u32)s | ((u32)(d & 511) << 17);
                cb_r[k] = d >> 9;
                atomicAdd(&hist[cb_r[k]], 1);
            }
        }
        __syncthreads();

        // 2) exclusive scan over 196 counts
        int c = (t < NCB) ? hist[t] : 0;
        int x = c;
        #pragma unroll
        for (int dd = 1; dd < 64; dd <<= 1) {
            int y = __shfl_up(x, dd);
            if ((t & 63) >= dd) x += y;
        }
        if ((t & 63) == 63) ws4[t >> 6] = x;
        __syncthreads();
        int wb = 0;
        #pragma unroll
        for (int k2 = 0; k2 < 4; ++k2) wb += (k2 < (t >> 6)) ? ws4[k2] : 0;
        int bex = wb + x - c;
        if (t < NCB) base[t] = bex;
        if (t == 0) base[NCB] = EPB;
        __syncthreads();
        if (t < NCB) hist[t] = bex;             // cursor = base
        __syncthreads();

        // 3) scatter into bucket-ordered LDS (the 4B chaos stays in LDS)
        #pragma unroll
        for (int k = 0; k < EPT; ++k) {
            int idx = t + k * 256;
            if (idx < EPB) {
                int p = atomicAdd(&hist[cb_r[k]], 1);
                lent[p] = ent_r[k];
                lcb[p] = (u8)cb_r[k];
            }
        }
        __syncthreads();

        // 4) streaming write: each bucket run starts 64B-aligned (b*192) ->
        // consecutive lanes produce full-line stores.
        for (int i = t; i < EPB; i += 256) {
            int cbv = (int)lcb[i];
            int off = i - base[cbv];
            if (off < CELLCAP)
                bkt[(size_t)cbv * BSLOT + (size_t)b * CELLCAP + off] = lent[i];
        }
        if (t < NCB) {
            int cntv = hist[t] - base[t];
            gcnt[t * FILLB + b] = (cntv > CELLCAP) ? CELLCAP : cntv;
        }
        return;
    }

    if (bid < FILLB + 128) {
        // ---- cast_w: fp32 [128][256] -> bf16, k-columns permuted to slot order
        int i = (bid - FILLB) * 256 + t;             // 32768
        int o = i >> 8;
        int p = i & 255;
        int bse = p & 128;
        int ph = p & 127;
        int f = (ph >> 1) + ((ph & 1) << 6);
        Wb[i] = f2bf(W[o * 256 + bse + f]);
        return;
    }

    // ---- cast_h: fp32 -> bf16 pair-permuted (u32 j = feats j, j+64)
    {
        int i = (bid - FILLB - 128) * 256 + t;       // 1.6M
        int r = i >> 4;
        int pc = (i & 15) * 8;
        const float* hr = h + (size_t)r * DF;
        int fb = pc >> 1;
        float4 a = *(const float4*)(hr + fb);
        float4 bv = *(const float4*)(hr + fb + 64);
        union { u16 s[8]; uint4 v; } u;
        u.s[0] = f2bf(a.x); u.s[1] = f2bf(bv.x);
        u.s[2] = f2bf(a.y); u.s[3] = f2bf(bv.y);
        u.s[4] = f2bf(a.z); u.s[5] = f2bf(bv.z);
        u.s[6] = f2bf(a.w); u.s[7] = f2bf(bv.w);
        *(uint4*)(hb + (size_t)i * 8) = u.v;
    }
}

// One block per bucket. ALL scatter happens in LDS; global writes are ONE
// streaming pass of full lines (this is what rebin2 got wrong: its in-place
// CSR scatter was 1.6M scattered 4B global stores = the round-0/7 wall).
// Phase 1: thread t reads writer-cell t's entries -> LDS-atomic scatter into
// csr[512][CAP]. Phase 2: barrier. Phase 3: stream the 96KB region back
// in-place (block-exclusive -> race-free).
__global__ void __launch_bounds__(512)
rebin3(const int* __restrict__ gcnt, u32* __restrict__ bkt, u8* __restrict__ deg) {
    extern __shared__ __align__(16) u32 smem[];
    u32* csr = smem;                              // [512][CAP] = 98304 B
    int* cnt2 = (int*)(smem + 512 * CAP);         // 2048 B

    const int t = threadIdx.x;
    const int cb = blockIdx.x;

    cnt2[t] = 0;
    __syncthreads();

    // phase 1: scatter my cell's entries into the LDS CSR
    {
        int c = gcnt[cb * FILLB + t];             // layout [bucket][writer]
        const u32* cell = bkt + (size_t)cb * BSLOT + (size_t)t * CELLCAP;
        for (int i = 0; i < c; ++i) {
            u32 e = cell[i];
            int ld = (int)((e >> 17) & 511u);
            int pos = atomicAdd(&cnt2[ld], 1);
            if (pos < CAP) csr[ld * CAP + pos] = e & 0x1FFFFu;
        }
    }
    __syncthreads();

    // phase 3: streaming full-line writeback (in-place over the same region)
    for (int i = t; i < 512 * CAP; i += 512)
        bkt[(size_t)cb * BSLOT + i] = csr[i];
    {
        int node = cb * 512 + t;
        if (node < NN) {
            int dv = cnt2[t];
            deg[node] = (u8)((dv > 255) ? 255 : dv);
        }
    }
}

// Fused: contiguous CSR copy (12 KB dense) -> per-lane register gather-mean
// -> [h|mean] @ W^T (MFMA) -> bias/L2norm/relu. 64 nodes/block, 4 waves.
__global__ void __launch_bounds__(256)
sage_fused(const u16* __restrict__ hb, const u8* __restrict__ deg,
           const u32* __restrict__ bkt, const u16* __restrict__ Wb,
           const float* __restrict__ bias, float* __restrict__ out) {
    __shared__ __align__(16) u16 xm[64 * XP2];   // 16.9 KB
    u32* nbr = (u32*)xm;                          // alias bytes [0, 12288)
    int* dgl = (int*)(xm + 6144);                 // alias bytes [12288, 12544)

    const int t = threadIdx.x;
    const int node0 = blockIdx.x * 64;

    // ---- A0: contiguous copy of 64 node lists (64*48 u32 = 768 uint4)
    {
        const uint4* srcp = (const uint4*)(bkt + (size_t)(node0 >> 9) * BSLOT
                                               + (size_t)(node0 & 511) * 48);
        uint4* dst = (uint4*)nbr;
        #pragma unroll
        for (int k = 0; k < 3; ++k) dst[t + k * 256] = srcp[t + k * 256];
    }
    if (t < 64) {
        int node = node0 + t;
        dgl[t] = (node < NN) ? (int)deg[node] : 0;
    }
    __syncthreads();

    // ---- A1: per-lane register gather-mean; 4 lanes/node x 32 slots
    const int grp = t >> 2;
    const int sub = t & 3;
    const int dg = dgl[grp];
    const int dgc = (dg < CAP) ? dg : CAP;

    float a[32];
    #pragma unroll
    for (int i = 0; i < 32; ++i) a[i] = 0.f;
    {
        const u32* nrow = nbr + grp * CAP;
        int src = (dgc > 0) ? (int)nrow[0] : 0;
        for (int p = 0; p < dgc; ++p) {
            int nsrc = (p + 1 < dgc) ? (int)nrow[p + 1] : 0;
            const uint4* hp = (const uint4*)((const u32*)hb + (size_t)src * 64 + sub * 16);
            #pragma unroll
            for (int qq = 0; qq < 4; ++qq) {
                uint4 v = hp[qq];
                u32 wv[4] = {v.x, v.y, v.z, v.w};
                #pragma unroll
                for (int m = 0; m < 4; ++m) {
                    union { u32 i; float f; } lo, hi;
                    lo.i = wv[m] << 16;
                    hi.i = wv[m] & 0xFFFF0000u;
                    a[qq * 8 + m * 2 + 0] += lo.f;
                    a[qq * 8 + m * 2 + 1] += hi.f;
                }
            }
            src = nsrc;
        }
    }

    // ---- B: write bf16 mean into xm (aliases nbr after barrier)
    float rinv = 1.0f / fmaxf((float)dg, 1.0f);
    __syncthreads();
    {
        u16* dstm = xm + grp * XP2 + sub * 32;
        #pragma unroll
        for (int qq = 0; qq < 4; ++qq) {
            union { u16 s[8]; uint4 v; } pk;
            #pragma unroll
            for (int m = 0; m < 8; ++m) pk.s[m] = f2bf(a[qq * 8 + m] * rinv);
            *(uint4*)(dstm + qq * 8) = pk.v;
        }
    }
    __syncthreads();

    // ---- MFMA: K=256; k<128 (own h) from global hb, k>=128 (mean) from LDS
    const int w = t >> 6;
    const int l = t & 63;
    const int lane15 = l & 15;
    const int quad = l >> 4;

    int arow = node0 + w * 16 + lane15; if (arow >= NN) arow = NN - 1;
    const u16* ag = hb + (size_t)arow * DF + quad * 8;
    const u16* am = xm + (w * 16 + lane15) * XP2 + quad * 8;
    const u16* brow = Wb + (size_t)lane15 * 256 + quad * 8;

    f32x4 acc[8];
    #pragma unroll
    for (int nt = 0; nt < 8; ++nt) acc[nt] = (f32x4){0.f, 0.f, 0.f, 0.f};

    #pragma unroll
    for (int ks = 0; ks < 4; ++ks) {
        short8 af = *(const short8*)(ag + ks * 32);
        #pragma unroll
        for (int nt = 0; nt < 8; ++nt) {
            short8 bf = *(const short8*)(brow + nt * 16 * 256 + ks * 32);
            acc[nt] = __builtin_amdgcn_mfma_f32_16x16x32_bf16(af, bf, acc[nt], 0, 0, 0);
        }
    }
    #pragma unroll
    for (int ks = 0; ks < 4; ++ks) {
        short8 af = *(const short8*)(am + ks * 32);
        #pragma unroll
        for (int nt = 0; nt < 8; ++nt) {
            short8 bf = *(const short8*)(brow + nt * 16 * 256 + 128 + ks * 32);
            acc[nt] = __builtin_amdgcn_mfma_f32_16x16x32_bf16(af, bf, acc[nt], 0, 0, 0);
        }
    }

    // ---- epilogue: +bias, row L2-norm (16-lane reduce), relu, fp32 out
    float bb[8];
    #pragma unroll
    for (int nt = 0; nt < 8; ++nt) bb[nt] = bias[nt * 16 + lane15];

    #pragma unroll
    for (int r = 0; r < 4; ++r) {
        float v[8]; float ss = 0.f;
        #pragma unroll
        for (int nt = 0; nt < 8; ++nt) { v[nt] = acc[nt][r] + bb[nt]; ss += v[nt] * v[nt]; }
        ss += __shfl_xor(ss, 1);
        ss += __shfl_xor(ss, 2);
        ss += __shfl_xor(ss, 4);
        ss += __shfl_xor(ss, 8);
        float sc = 1.0f / fmaxf(sqrtf(ss), 1e-12f);
        int row = node0 + w * 16 + quad * 4 + r;
        if (row < NN) {
            float* orow = out + (size_t)row * DF + lane15;
            #pragma unroll
            for (int nt = 0; nt < 8; ++nt) orow[nt * 16] = fmaxf(v[nt], 0.f) * sc;
        }
    }
}

extern "C" void kernel_launch(void* const* d_in, const int* in_sizes, int n_in,
                              void* d_out, int out_size, void* d_ws, size_t ws_size,
                              hipStream_t stream) {
    const float* h   = (const float*)d_in[0];
    const float* W   = (const float*)d_in[1];
    const float* b   = (const float*)d_in[2];
    const int*   esc = (const int*)d_in[3];
    const int*   edt = (const int*)d_in[4];
    float* out = (float*)d_out;

    // ws: Wb 64K | hb 25.6M | bkt 196*24576*4 = 19.27M | gcnt 401K | deg 100K
    //   ~= 45.4 MB. No memsets (gcnt/deg written unconditionally).
    char* ws = (char*)d_ws;
    u16* Wb   = (u16*)(ws);
    u16* hb   = (u16*)(ws + 65536);
    u32* bkt  = (u32*)(ws + 65536 + 25600000);
    int* gcnt = (int*)(ws + 65536 + 25600000 + 19267584);
    u8*  deg  = (u8*) (ws + 65536 + 25600000 + 19267584 + 401408);

    static bool attr_set = false;
    if (!attr_set) {
        hipFuncSetAttribute((const void*)rebin3,
                            hipFuncAttributeMaxDynamicSharedMemorySize, RB_LDS);
        attr_set = true;
    }

    prep<<<FILLB + 128 + 6250, 256, 0, stream>>>(h, W, esc, edt, hb, Wb, bkt, gcnt);
    rebin3<<<NCB, 512, RB_LDS, stream>>>(gcnt, bkt, deg);
    sage_fused<<<NB, 256, 0, stream>>>(hb, deg, bkt, Wb, b, out);
}